// Round 1
// 414.963 us; speedup vs baseline: 1.0460x; 1.0460x over previous
//
#include <hip/hip_runtime.h>
#include <hip/hip_bf16.h>

#define WW 128
#define GG 64
#define GN_EPS 1e-5f
#define SCAN_B 1024

typedef __attribute__((ext_vector_type(8))) short short8;
typedef __attribute__((ext_vector_type(4))) float floatx4;

__device__ inline float bf2f(__hip_bfloat16 h) { return __bfloat162float(h); }

// ---------------- GraphNorm stats: per-graph sum, sumsq, count ----------------
// v2: 4-row batched loads (8 independent loads in flight) before the serial
// boundary logic; graph boundaries are rare (63 total across the dataset).
__global__ __launch_bounds__(128) void stats_kernel(
    const float* __restrict__ x, const int* __restrict__ batch, int N,
    float* __restrict__ gsum, float* __restrict__ gsumsq, float* __restrict__ gcnt)
{
    int w = threadIdx.x;
    int row0 = blockIdx.x * 64;
    int row1 = min(row0 + 64, N);
    float s = 0.f, ss = 0.f;
    int cur = batch[row0];
    int cnt = 0;
    auto flush = [&]() {
        atomicAdd(&gsum[cur * WW + w], s);
        atomicAdd(&gsumsq[cur * WW + w], ss);
        if (w == 0) atomicAdd(&gcnt[cur], (float)cnt);
        s = 0.f; ss = 0.f; cnt = 0;
    };
    int i = row0;
    for (; i + 4 <= row1; i += 4) {
        int g0 = batch[i + 0], g1 = batch[i + 1], g2 = batch[i + 2], g3 = batch[i + 3];
        float v0 = x[(size_t)(i + 0) * WW + w];
        float v1 = x[(size_t)(i + 1) * WW + w];
        float v2 = x[(size_t)(i + 2) * WW + w];
        float v3 = x[(size_t)(i + 3) * WW + w];
        if (g0 != cur) { flush(); cur = g0; }
        s += v0; ss += v0 * v0; ++cnt;
        if (g1 != cur) { flush(); cur = g1; }
        s += v1; ss += v1 * v1; ++cnt;
        if (g2 != cur) { flush(); cur = g2; }
        s += v2; ss += v2 * v2; ++cnt;
        if (g3 != cur) { flush(); cur = g3; }
        s += v3; ss += v3 * v3; ++cnt;
    }
    for (; i < row1; ++i) {
        int g = batch[i];
        float v = x[(size_t)i * WW + w];
        if (g != cur) { flush(); cur = g; }
        s += v; ss += v * v; ++cnt;
    }
    flush();
}

// ---------------- fold stats into per-(g,w) affine scale/shift ----------------
__global__ __launch_bounds__(256) void finalize_kernel(
    const float* __restrict__ gsum, const float* __restrict__ gsumsq,
    const float* __restrict__ gcnt,
    const float* __restrict__ wgt, const float* __restrict__ bias,
    const float* __restrict__ ms,
    float* __restrict__ scalev, float* __restrict__ shiftv)
{
    int idx = blockIdx.x * blockDim.x + threadIdx.x;
    if (idx >= GG * WW) return;
    int g = idx >> 7, w = idx & (WW - 1);
    float cnt = gcnt[g];
    float inv = cnt > 0.f ? 1.f / cnt : 0.f;
    float mean = gsum[idx] * inv;
    float msw = ms[w];
    float var = gsumsq[idx] * inv - mean * mean * msw * (2.f - msw);
    var = fmaxf(var, 0.f);
    float sc = wgt[w] * rsqrtf(var + GN_EPS);
    scalev[idx] = sc;
    shiftv[idx] = bias[w] - sc * msw * mean;
}

// ---------------- normalize: xn = scale*x + shift (bf16 out), float4 lanes ----
__global__ __launch_bounds__(256) void normalize_kernel(
    const float* __restrict__ x, const int* __restrict__ batch,
    const float* __restrict__ scalev, const float* __restrict__ shiftv,
    __hip_bfloat16* __restrict__ xn, int N)
{
    size_t tid = (size_t)blockIdx.x * blockDim.x + threadIdx.x;   // one per 4 elems
    if (tid >= (size_t)N * (WW / 4)) return;
    int row = (int)(tid >> 5);
    int c4 = (int)(tid & 31) * 4;
    int g = batch[row];
    float4 v = *(const float4*)(x + (size_t)row * WW + c4);
    float4 sc = *(const float4*)(scalev + (size_t)g * WW + c4);
    float4 sh = *(const float4*)(shiftv + (size_t)g * WW + c4);
    __hip_bfloat162 o0, o1;
    o0.x = __float2bfloat16(sc.x * v.x + sh.x);
    o0.y = __float2bfloat16(sc.y * v.y + sh.y);
    o1.x = __float2bfloat16(sc.z * v.z + sh.z);
    o1.y = __float2bfloat16(sc.w * v.w + sh.w);
    union { __hip_bfloat162 h[2]; uint2 u; } pk;
    pk.h[0] = o0; pk.h[1] = o1;
    *(uint2*)(xn + (size_t)row * WW + c4) = pk.u;
}

// ---------------- convert fp32 weight matrices -> bf16 ----------------
__global__ __launch_bounds__(256) void cvt_w_kernel(
    const float* __restrict__ w0, const float* __restrict__ w1,
    const float* __restrict__ w2, const float* __restrict__ w3,
    __hip_bfloat16* __restrict__ dst)
{
    int idx = blockIdx.x * blockDim.x + threadIdx.x;   // 0 .. 4*16384-1
    int m = idx >> 14;
    int o = idx & 16383;
    const float* src = (m == 0) ? w0 : (m == 1) ? w1 : (m == 2) ? w2 : w3;
    dst[idx] = __float2bfloat16(src[o]);
}

// ---------------- CSR build: histogram over dst ----------------
__global__ __launch_bounds__(256) void hist_kernel(
    const int* __restrict__ ei, int E, int* __restrict__ deg)
{
    int e = blockIdx.x * 256 + threadIdx.x;
    if (e < E) atomicAdd(&deg[ei[(size_t)E + e]], 1);
}

// ---------------- hierarchical exclusive scan (3 kernels) ----------------
__global__ __launch_bounds__(SCAN_B) void scan_blocks(
    const int* __restrict__ deg, int N, int* __restrict__ off, int* __restrict__ bsum)
{
    __shared__ int s[SCAN_B];
    int t = threadIdx.x;
    int i = blockIdx.x * SCAN_B + t;
    int v = (i < N) ? deg[i] : 0;
    s[t] = v; __syncthreads();
    for (int d = 1; d < SCAN_B; d <<= 1) {
        int tmp = (t >= d) ? s[t - d] : 0;
        __syncthreads();
        s[t] += tmp;
        __syncthreads();
    }
    if (i < N) off[i] = s[t] - v;                 // block-local exclusive
    if (t == SCAN_B - 1) bsum[blockIdx.x] = s[t]; // block total
}

__global__ __launch_bounds__(256) void scan_partials(int* __restrict__ bsum, int P)
{
    __shared__ int s[256];
    int t = threadIdx.x;
    int v = (t < P) ? bsum[t] : 0;
    s[t] = v; __syncthreads();
    for (int d = 1; d < 256; d <<= 1) {
        int tmp = (t >= d) ? s[t - d] : 0;
        __syncthreads();
        s[t] += tmp;
        __syncthreads();
    }
    if (t < P) bsum[t] = s[t] - v;                // exclusive, in place
}

__global__ __launch_bounds__(SCAN_B) void add_offsets(
    int* __restrict__ off, const int* __restrict__ bsum, int N)
{
    int i = blockIdx.x * SCAN_B + threadIdx.x;
    if (i < N) off[i] += bsum[blockIdx.x];
}

// ---------------- placement: ebuf[slot] = {src, weight} bucketed by dst ------
__global__ __launch_bounds__(256) void place_kernel(
    const int* __restrict__ ei, const float* __restrict__ ew,
    const int* __restrict__ off, int* __restrict__ cursor,
    int2* __restrict__ ebuf, int E)
{
    int e = blockIdx.x * 256 + threadIdx.x;
    if (e >= E) return;
    int dst = ei[(size_t)E + e];
    int slot = off[dst] + atomicAdd(&cursor[dst], 1);
    ebuf[slot] = make_int2(ei[e], __float_as_int(ew[e]));
}

// ---------------- gather v5: masked 4-wide main loop, no serial tail ----------
// One wave per node; lane owns 2 channels (bf16x2). Every iteration issues 4
// independent ebuf reads + 4 independent row loads; overhang lanes clamp to
// the last edge and multiply by weight 0 (cache-hit, no extra latency chain).
__global__ __launch_bounds__(256) void gather_kernel(
    const __hip_bfloat16* __restrict__ feat, const int2* __restrict__ ebuf,
    const int* __restrict__ off, const int* __restrict__ deg,
    __hip_bfloat16* __restrict__ aggbf, int N)
{
    int wave = threadIdx.x >> 6;
    int lane = threadIdx.x & 63;
    int node = blockIdx.x * 4 + wave;
    if (node >= N) return;
    int start = off[node];
    int d = deg[node];
    const __hip_bfloat162* f2 = (const __hip_bfloat162*)feat;

    float ax0 = 0.f, ay0 = 0.f, ax1 = 0.f, ay1 = 0.f;
    float ax2 = 0.f, ay2 = 0.f, ax3 = 0.f, ay3 = 0.f;
    int last = start + d - 1;                     // d==0 -> loop skipped
    for (int k = start; k <= last; k += 4) {
        int i1 = min(k + 1, last);
        int i2 = min(k + 2, last);
        int i3 = min(k + 3, last);
        int2 p0 = ebuf[k];
        int2 p1 = ebuf[i1];
        int2 p2 = ebuf[i2];
        int2 p3 = ebuf[i3];
        __hip_bfloat162 v0 = f2[(size_t)p0.x * 64 + lane];
        __hip_bfloat162 v1 = f2[(size_t)p1.x * 64 + lane];
        __hip_bfloat162 v2 = f2[(size_t)p2.x * 64 + lane];
        __hip_bfloat162 v3 = f2[(size_t)p3.x * 64 + lane];
        float w0 = __int_as_float(p0.y);
        float w1 = (k + 1 <= last) ? __int_as_float(p1.y) : 0.f;
        float w2 = (k + 2 <= last) ? __int_as_float(p2.y) : 0.f;
        float w3 = (k + 3 <= last) ? __int_as_float(p3.y) : 0.f;
        ax0 += w0 * bf2f(v0.x); ay0 += w0 * bf2f(v0.y);
        ax1 += w1 * bf2f(v1.x); ay1 += w1 * bf2f(v1.y);
        ax2 += w2 * bf2f(v2.x); ay2 += w2 * bf2f(v2.y);
        ax3 += w3 * bf2f(v3.x); ay3 += w3 * bf2f(v3.y);
    }
    float ax = (ax0 + ax1) + (ax2 + ax3);
    float ay = (ay0 + ay1) + (ay2 + ay3);

    __hip_bfloat162 o;
    o.x = __float2bfloat16(ax);
    o.y = __float2bfloat16(ay);
    ((__hip_bfloat162*)(aggbf + (size_t)node * WW))[lane] = o;
}

// ---------------- fused GEMM v5: streamed-W, low-pressure, pipelined ---------
// y = act([A1|A2] @ [Wrel;Wroot]^T + b) (+resid). K=256. Wave owns 32 cols.
// W fragments are loaded per-kc (same load count as the old persistent-W
// version — it only used them for one tile anyway — but liveness drops from
// 64 VGPR to 8, so with the 128-reg cap the scheduler can pipeline 2-3 kc
// iterations of A/W loads and occupancy doubles: that attacks the measured
// latency-bound profile (1.7 TB/s @ 27% occupancy, all pipes idle).
// C/D layout: col=lane&15, row=(lane>>4)*4+reg (m89-verified).
template <bool OUT_BF16>
__global__ __launch_bounds__(256, 4) void gemm_kernel(
    const __hip_bfloat16* __restrict__ A1, const __hip_bfloat16* __restrict__ A2,
    const __hip_bfloat16* __restrict__ Wrel, const __hip_bfloat16* __restrict__ Wroot,
    const float* __restrict__ bias, const float* __restrict__ resid,
    void* __restrict__ outv, int N, int leaky)
{
    int wave = threadIdx.x >> 6;
    int lane = threadIdx.x & 63;
    int q = lane >> 4;
    int r16 = lane & 15;
    int rb = blockIdx.x * 64;

    floatx4 acc[4][2];
#pragma unroll
    for (int r = 0; r < 4; ++r)
#pragma unroll
        for (int tt = 0; tt < 2; ++tt) acc[r][tt] = (floatx4){0.f, 0.f, 0.f, 0.f};

#pragma unroll
    for (int kc = 0; kc < 8; ++kc) {
        const __hip_bfloat16* Asel = (kc < 4) ? A1 : A2;
        const __hip_bfloat16* Wsel = (kc < 4) ? Wrel : Wroot;
        int koff = (kc & 3) * 32 + q * 8;
        short8 wf0 = *(const short8*)(Wsel + ((size_t)((wave * 2 + 0) * 16 + r16) * WW + koff));
        short8 wf1 = *(const short8*)(Wsel + ((size_t)((wave * 2 + 1) * 16 + r16) * WW + koff));
        short8 af[4];
#pragma unroll
        for (int r = 0; r < 4; ++r) {
            int ar = rb + r * 16 + r16;
            if (ar >= N) ar = N - 1;       // clamp loads; stores masked
            af[r] = *(const short8*)(Asel + ((size_t)ar * WW + koff));
        }
#pragma unroll
        for (int r = 0; r < 4; ++r) {
            acc[r][0] = __builtin_amdgcn_mfma_f32_16x16x32_bf16(af[r], wf0, acc[r][0], 0, 0, 0);
            acc[r][1] = __builtin_amdgcn_mfma_f32_16x16x32_bf16(af[r], wf1, acc[r][1], 0, 0, 0);
        }
    }

    float bcol[2];
#pragma unroll
    for (int tt = 0; tt < 2; ++tt) bcol[tt] = bias[(wave * 2 + tt) * 16 + r16];

#pragma unroll
    for (int tt = 0; tt < 2; ++tt) {
        int col = (wave * 2 + tt) * 16 + r16;
#pragma unroll
        for (int r = 0; r < 4; ++r)
#pragma unroll
            for (int rr = 0; rr < 4; ++rr) {
                int row = rb + r * 16 + q * 4 + rr;
                if (row < N) {
                    float v = acc[r][tt][rr] + bcol[tt];
                    if (leaky) v = v >= 0.f ? v : 0.1f * v;
                    if (resid) v += resid[(size_t)row * WW + col];
                    if (OUT_BF16)
                        ((__hip_bfloat16*)outv)[(size_t)row * WW + col] = __float2bfloat16(v);
                    else
                        ((float*)outv)[(size_t)row * WW + col] = v;
                }
            }
    }
}

extern "C" void kernel_launch(void* const* d_in, const int* in_sizes, int n_in,
                              void* d_out, int out_size, void* d_ws, size_t ws_size,
                              hipStream_t stream) {
    const float* x      = (const float*)d_in[0];
    const int*   ei     = (const int*)d_in[1];
    const float* ew     = (const float*)d_in[2];
    const int*   batch  = (const int*)d_in[3];
    const float* gnw    = (const float*)d_in[4];
    const float* gnb    = (const float*)d_in[5];
    const float* gnm    = (const float*)d_in[6];
    const float* Wrel1  = (const float*)d_in[7];
    const float* brel1  = (const float*)d_in[8];
    const float* Wroot1 = (const float*)d_in[9];
    const float* Wrel2  = (const float*)d_in[10];
    const float* brel2  = (const float*)d_in[11];
    const float* Wroot2 = (const float*)d_in[12];

    int N = in_sizes[0] / WW;
    int E = in_sizes[1] / 2;
    int P = (N + SCAN_B - 1) / SCAN_B;   // scan partial count (98 for N=100k)
    int ntiles = (N + 63) / 64;

    // workspace layout (8-byte aligned):
    // aggbf | xn | y1 (bf16 N*W each) | Wb (bf16 4*W*W) | ebuf (int2 E)
    // | deg | cursor | gsum | gsumsq | gcnt | scalev | shiftv | off | bsum
    __hip_bfloat16* aggbf = (__hip_bfloat16*)d_ws;
    __hip_bfloat16* xn = aggbf + (size_t)N * WW;
    __hip_bfloat16* y1 = xn + (size_t)N * WW;
    __hip_bfloat16* Wb = y1 + (size_t)N * WW;       // [Wrel1|Wroot1|Wrel2|Wroot2]
    int2* ebuf   = (int2*)(Wb + 4 * WW * WW);
    int*  deg    = (int*)(ebuf + E);
    int*  cursor = deg + N;
    float* gsum   = (float*)(cursor + N);
    float* gsumsq = gsum + GG * WW;
    float* gcnt   = gsumsq + GG * WW;               // GG floats
    float* scalev = gcnt + GG;
    float* shiftv = scalev + GG * WW;
    int*  off    = (int*)(shiftv + GG * WW);
    int*  bsum   = off + N;

    // one memset covers deg, cursor, gsum, gsumsq, gcnt (contiguous)
    hipMemsetAsync(deg, 0, ((size_t)2 * N + 2 * GG * WW + GG) * sizeof(int), stream);

    // ---- CSR build (once; reused by both layers) ----
    hist_kernel<<<(E + 255) / 256, 256, 0, stream>>>(ei, E, deg);
    scan_blocks<<<P, SCAN_B, 0, stream>>>(deg, N, off, bsum);
    scan_partials<<<1, 256, 0, stream>>>(bsum, P);
    add_offsets<<<P, SCAN_B, 0, stream>>>(off, bsum, N);
    place_kernel<<<(E + 255) / 256, 256, 0, stream>>>(ei, ew, off, cursor, ebuf, E);

    // ---- GraphNorm ----
    cvt_w_kernel<<<(4 * WW * WW) / 256, 256, 0, stream>>>(Wrel1, Wroot1, Wrel2, Wroot2, Wb);
    stats_kernel<<<(N + 63) / 64, 128, 0, stream>>>(x, batch, N, gsum, gsumsq, gcnt);
    finalize_kernel<<<(GG * WW + 255) / 256, 256, 0, stream>>>(
        gsum, gsumsq, gcnt, gnw, gnb, gnm, scalev, shiftv);
    normalize_kernel<<<(int)(((size_t)N * (WW / 4) + 255) / 256), 256, 0, stream>>>(
        x, batch, scalev, shiftv, xn, N);

    // ---- layer 1: gather + GEMM(+bias+leaky) ----
    gather_kernel<<<(N + 3) / 4, 256, 0, stream>>>(xn, ebuf, off, deg, aggbf, N);
    gemm_kernel<true><<<ntiles, 256, 0, stream>>>(
        aggbf, xn, Wb, Wb + WW * WW, brel1, nullptr, y1, N, 1);

    // ---- layer 2: gather + GEMM(+bias+residual) ----
    gather_kernel<<<(N + 3) / 4, 256, 0, stream>>>(y1, ebuf, off, deg, aggbf, N);
    gemm_kernel<false><<<ntiles, 256, 0, stream>>>(
        aggbf, y1, Wb + 2 * WW * WW, Wb + 3 * WW * WW, brel2, x, d_out, N, 0);
}